// Round 6
// baseline (279.423 us; speedup 1.0000x reference)
//
#include <hip/hip_runtime.h>
#include <hip/hip_cooperative_groups.h>

namespace cg = cooperative_groups;

// AlignOnlySubLayer: out[b,m,d] = main[b,m,d] - sum_c softmax_m(C·M^T)[c,m] * C[c,d]
// B=8, Lc=Lm=2048, D=128, fp32 in/out.
// Round-14: R13's cooperative mega-kernel with the compile fix (no LDS-pointer
// arrays: buffer pointers computed from parity index, addrspacecast stays out
// of static initializers). One dispatch, 512 blocks x 256 thr, 64 KB LDS,
// 2 blocks/CU co-resident, grid.sync() between phases.
//   Phase A: convert — Cbf/Mbf = bf16(ctx/main) swizzled; Lg = 0
//   Phase B: stats   — L[c] = sum_m exp(S-40), counted-vmcnt dbuf (R12 body)
//   Phase C: prep    — CtLf fragment records = bf16(C/L) (R12 mapping, 512-way)
//   Phase D: attend  — S=mfma(Cs,mf) swapped 32x32x16 -> exp/pack ->
//            shfl_xor(32) PV B-frag -> PV with coalesced CtLf tv (R12 body)
// Swizzle (Cbf/Mbf): 16B chunk pc = (lc&8)|((lc^row)&7); CtLf needs none.
// Fallback: R12's 4-kernel path if cooperative launch is rejected; tiny-ws
// fallback unchanged.

#define BATCH 8
#define L_SEQ 2048
#define DD 128
#define SHIFT 40.0f
#define LDA 136   // fallback/prep padded stride

typedef __attribute__((ext_vector_type(8))) short bf16x8;
typedef __attribute__((ext_vector_type(4))) short bf16x4;
typedef __attribute__((ext_vector_type(4))) float f32x4;
typedef __attribute__((ext_vector_type(16))) float f32x16;
typedef __attribute__((ext_vector_type(4))) unsigned int uint4v;

__device__ __forceinline__ short f2bf(float f) {
    unsigned u = __builtin_bit_cast(unsigned, f);
    return (short)((u + 0x8000u) >> 16);
}

__device__ __forceinline__ void gl2lds16(const short* g, short* l) {
    __builtin_amdgcn_global_load_lds(
        (const __attribute__((address_space(1))) unsigned int*)g,
        (__attribute__((address_space(3))) unsigned int*)l, 16, 0, 0);
}

__device__ __forceinline__ void waitv8() { asm volatile("s_waitcnt vmcnt(8)" ::: "memory"); }
__device__ __forceinline__ void waitv4() { asm volatile("s_waitcnt vmcnt(4)" ::: "memory"); }
__device__ __forceinline__ void waitv0() { asm volatile("s_waitcnt vmcnt(0)" ::: "memory"); }

template <int NT>
__device__ __forceinline__ void stage_tile(short* __restrict__ dst,
                                           const float* __restrict__ src,
                                           int nelts, int t) {
    for (int base = 0; base < nelts; base += NT * 8) {
        int flat = base + t * 8;
        const float4* p = (const float4*)(src + flat);
        float4 v0 = p[0];
        float4 v1 = p[1];
        bf16x8 s;
        s[0] = f2bf(v0.x); s[1] = f2bf(v0.y); s[2] = f2bf(v0.z); s[3] = f2bf(v0.w);
        s[4] = f2bf(v1.x); s[5] = f2bf(v1.y); s[6] = f2bf(v1.z); s[7] = f2bf(v1.w);
        int row = flat >> 7;
        int col = flat & 127;
        *(bf16x8*)&dst[row * LDA + col] = s;
    }
}

__global__ __launch_bounds__(256) void zero_kernel(float* __restrict__ p, int n) {
    int i = blockIdx.x * 256 + threadIdx.x;
    if (i < n) p[i] = 0.0f;
}

// ---------------------------------------------------------------------------
// Mega kernel (cooperative, grid = 512 x 256)
// ---------------------------------------------------------------------------

__global__ __launch_bounds__(256, 2) void mega_kernel(const float* __restrict__ ctx,
                                                      const float* __restrict__ mn,
                                                      short* __restrict__ Cbf,
                                                      short* __restrict__ Mbf,
                                                      short* __restrict__ CtLf,
                                                      float* __restrict__ Lg,
                                                      float* __restrict__ out) {
    __shared__ __align__(16) char smem[65536];
    cg::grid_group grid = cg::this_grid();

    int bid = blockIdx.x;
    int t = threadIdx.x;
    int w = t >> 6;
    int l = t & 63;
    int b = bid & 7;            // XCD batch affinity for phases B/D

    // ---------------- Phase A: convert + zero Lg --------------------------
    {
        int tid = bid * 256 + t;                 // 0..131071
        if (tid < BATCH * L_SEQ) Lg[tid] = 0.0f;
        const int half = BATCH * L_SEQ * DD / 8; // 262144 chunks per tensor
        #pragma unroll
        for (int k = 0; k < 4; ++k) {
            int id = tid + k * 131072;           // covers 0..524287
            const float* src;
            short* dst;
            if (id < half) { src = ctx; dst = Cbf; }
            else           { id -= half; src = mn; dst = Mbf; }
            int row = id >> 4;
            int lc = id & 15;
            const float4* p = (const float4*)(src + ((size_t)row << 7) + lc * 8);
            float4 v0 = p[0];
            float4 v1 = p[1];
            bf16x8 s;
            s[0] = f2bf(v0.x); s[1] = f2bf(v0.y); s[2] = f2bf(v0.z); s[3] = f2bf(v0.w);
            s[4] = f2bf(v1.x); s[5] = f2bf(v1.y); s[6] = f2bf(v1.z); s[7] = f2bf(v1.w);
            int pc = (lc & 8) | ((lc ^ row) & 7);
            *(bf16x8*)&dst[((size_t)row << 7) + pc * 8] = s;
        }
    }

    grid.sync();

    // ---------------- Phase B: stats (R12 body) ---------------------------
    {
        short* Cs = (short*)smem;                         // 32 KB

        int r2 = bid >> 3;
        int mc = r2 & 3;
        int ct = r2 >> 2;
        int a15 = l & 15;
        int q = l >> 4;
        int h = a15 & 7;
        int cw = (w & 1) * 64;
        int mw = (w >> 1) * 32;

        const short* gC = Cbf + ((size_t)(b * L_SEQ + ct * 128)) * DD;
        const short* gM = Mbf + ((size_t)(b * L_SEQ + mc * 512)) * DD;

        #pragma unroll
        for (int ii = 0; ii < 8; ++ii) {
            int inst = w * 8 + ii;
            gl2lds16(gC + inst * 512 + l * 8, Cs + inst * 512);
        }
        #pragma unroll
        for (int ii = 0; ii < 4; ++ii) {
            int inst = w * 4 + ii;
            gl2lds16(gM + inst * 512 + l * 8, (short*)(smem + 32768) + inst * 512);
        }
        #pragma unroll
        for (int ii = 0; ii < 4; ++ii) {
            int inst = w * 4 + ii;
            gl2lds16(gM + (size_t)64 * DD + inst * 512 + l * 8,
                     (short*)(smem + 49152) + inst * 512);
        }

        waitv8();
        __builtin_amdgcn_s_barrier();
        __builtin_amdgcn_sched_barrier(0);

        bf16x8 af[4][4];
        #pragma unroll
        for (int ks = 0; ks < 4; ++ks) {
            int aoff = ((ks * 4 + q) ^ h) * 8;
            #pragma unroll
            for (int i = 0; i < 4; ++i)
                af[ks][i] = *(const bf16x8*)&Cs[(cw + i * 16 + a15) * 128 + aoff];
        }

        float ls[4][4] = {};

        for (int ms = 0; ms < 8; ++ms) {
            int bp = ms & 1;
            short* Msb = (short*)(smem + 32768 + bp * 16384);
            if (ms < 7) waitv4(); else waitv0();
            __builtin_amdgcn_s_barrier();
            __builtin_amdgcn_sched_barrier(0);

            f32x4 acc[4][2];
            #pragma unroll
            for (int i = 0; i < 4; ++i)
                #pragma unroll
                for (int j = 0; j < 2; ++j) {
                    f32x4 z = {0.f, 0.f, 0.f, 0.f};
                    acc[i][j] = z;
                }
            #pragma unroll
            for (int ks = 0; ks < 4; ++ks) {
                int aoff = ((ks * 4 + q) ^ h) * 8;
                bf16x8 bv[2];
                #pragma unroll
                for (int j = 0; j < 2; ++j)
                    bv[j] = *(const bf16x8*)&Msb[(mw + j * 16 + a15) * 128 + aoff];
                #pragma unroll
                for (int i = 0; i < 4; ++i)
                    #pragma unroll
                    for (int j = 0; j < 2; ++j)
                        acc[i][j] = __builtin_amdgcn_mfma_f32_16x16x32_bf16(af[ks][i], bv[j], acc[i][j], 0, 0, 0);
            }

            #pragma unroll
            for (int j = 0; j < 2; ++j)
                #pragma unroll
                for (int i = 0; i < 4; ++i)
                    #pragma unroll
                    for (int r = 0; r < 4; ++r)
                        ls[i][r] += __expf(acc[i][j][r] - SHIFT);

            __builtin_amdgcn_s_barrier();
            __builtin_amdgcn_sched_barrier(0);
            if (ms + 2 < 8) {
                #pragma unroll
                for (int ii = 0; ii < 4; ++ii) {
                    int inst = w * 4 + ii;
                    gl2lds16(gM + (size_t)(ms + 2) * 64 * DD + inst * 512 + l * 8,
                             Msb + inst * 512);
                }
            }
        }

        #pragma unroll
        for (int i = 0; i < 4; ++i)
            #pragma unroll
            for (int r = 0; r < 4; ++r) {
                float v = ls[i][r];
                v += __shfl_xor(v, 1);
                v += __shfl_xor(v, 2);
                v += __shfl_xor(v, 4);
                v += __shfl_xor(v, 8);
                ls[i][r] = v;
            }
        if (a15 == 0) {
            #pragma unroll
            for (int i = 0; i < 4; ++i) {
                int c = ct * 128 + cw + i * 16 + q * 4;
                #pragma unroll
                for (int r = 0; r < 4; ++r)
                    atomicAdd(&Lg[(size_t)b * L_SEQ + c + r], ls[i][r]);
            }
        }
    }

    grid.sync();

    // ---------------- Phase C: prep (quarter-tiles, 512-way) --------------
    {
        short* Ts = (short*)smem;                  // 32 * LDA shorts = 8704 B
        float* invL = (float*)(smem + 8704);       // 32 floats

        int j = bid >> 3;        // 0..63
        int cc = j >> 2;         // 128-c window
        int qq = j & 3;          // quarter (32 c)

        if (t < 32) invL[t] = 1.0f / Lg[(size_t)b * L_SEQ + cc * 128 + qq * 32 + t];
        __syncthreads();

        const float* src = ctx + ((size_t)(b * L_SEQ + cc * 128 + qq * 32)) * DD;
        #pragma unroll
        for (int i = 0; i < 2; ++i) {
            int flat = i * 2048 + t * 8;
            int r = flat >> 7;
            int c = flat & 127;
            const float4* p = (const float4*)(src + flat);
            float4 v0 = p[0];
            float4 v1 = p[1];
            float il = invL[r];
            bf16x8 s;
            s[0] = f2bf(v0.x * il); s[1] = f2bf(v0.y * il); s[2] = f2bf(v0.z * il); s[3] = f2bf(v0.w * il);
            s[4] = f2bf(v1.x * il); s[5] = f2bf(v1.y * il); s[6] = f2bf(v1.z * il); s[7] = f2bf(v1.w * il);
            *(bf16x8*)&Ts[r * LDA + c] = s;
        }
        __syncthreads();

        // 8 records (dg,ks2) x 64 lane-slots = 512 slots; 2 per thread.
        #pragma unroll
        for (int i = 0; i < 2; ++i) {
            int slot = i * 256 + t;
            int recl = slot >> 6;       // 0..7 = dg*2 + ks2
            int l2  = slot & 63;
            int dgg = recl >> 1;
            int ks2 = recl & 1;
            int la2 = l2 & 31;
            int hi2 = l2 >> 5;
            int d   = dgg * 32 + la2;
            int rb  = (ks2 * 2 + hi2) * 8;   // local c row base (0..31)
            bf16x8 v;
            #pragma unroll
            for (int jj = 0; jj < 8; ++jj) v[jj] = Ts[(rb + jj) * LDA + d];
            int rec = qq * 8 + recl;
            *(bf16x8*)&CtLf[((size_t)(b * 16 + cc) * 32 + rec) * 512 + l2 * 8] = v;
        }
        __syncthreads();
    }

    grid.sync();

    // ---------------- Phase D: attend (R12 body) --------------------------
    {
        int mtile = bid >> 3;      // 0..63, 32 m each
        int la = l & 31;
        int hi = l >> 5;
        int ch = w;

        int m_glob = mtile * 32 + la;
        int key7 = la & 7;

        bf16x8 mf[8];
        {
            const short* mrow = Mbf + ((size_t)(b * L_SEQ + m_glob)) * DD;
            #pragma unroll
            for (int ks = 0; ks < 8; ++ks) {
                int lc = ks * 2 + hi;
                int pc = (lc & 8) | ((lc ^ key7) & 7);
                mf[ks] = *(const bf16x8*)&mrow[pc * 8];
            }
        }

        auto stage = [&](int cs, int p) {
            short* Cw = (short*)(smem + p * 32768);
            const short* gC = Cbf + ((size_t)(b * L_SEQ + cs * 128)) * DD;
            #pragma unroll
            for (int ii = 0; ii < 8; ++ii) {
                int inst = w * 8 + ii;
                gl2lds16(gC + inst * 512 + l * 8, Cw + inst * 512);
            }
        };

        f32x16 o[4];
        #pragma unroll
        for (int dg = 0; dg < 4; ++dg)
            #pragma unroll
            for (int r = 0; r < 16; ++r) o[dg][r] = 0.0f;

        stage(0, 0);
        stage(1, 1);

        for (int cs = 0; cs < 16; ++cs) {
            int p = cs & 1;
            waitv8();
            __builtin_amdgcn_s_barrier();
            __builtin_amdgcn_sched_barrier(0);

            const short* gF = CtLf + ((size_t)((b * 16 + cs) * 4 + ch) * 8) * 512 + l * 8;
            bf16x8 tv[4][2];
            #pragma unroll
            for (int dg = 0; dg < 4; ++dg)
                #pragma unroll
                for (int ks2 = 0; ks2 < 2; ++ks2)
                    tv[dg][ks2] = *(const bf16x8*)&gF[(dg * 2 + ks2) * 512];

            const short* Cw = (const short*)(smem + p * 32768);

            f32x16 s;
            #pragma unroll
            for (int r = 0; r < 16; ++r) s[r] = 0.0f;
            int crow = ch * 32 + la;
            #pragma unroll
            for (int ks = 0; ks < 8; ++ks) {
                int lc = ks * 2 + hi;
                int pc = (lc & 8) | ((lc ^ key7) & 7);
                bf16x8 av = *(const bf16x8*)&Cw[crow * 128 + pc * 8];
                s = __builtin_amdgcn_mfma_f32_32x32x16_bf16(av, mf[ks], s, 0, 0, 0);
            }

            unsigned u[4][2];
            #pragma unroll
            for (int q = 0; q < 4; ++q)
                #pragma unroll
                for (int jj = 0; jj < 2; ++jj) {
                    float e0 = __expf(s[q * 4 + jj * 2]     - SHIFT);
                    float e1 = __expf(s[q * 4 + jj * 2 + 1] - SHIFT);
                    u[q][jj] = ((unsigned)(unsigned short)f2bf(e1) << 16)
                             |  (unsigned)(unsigned short)f2bf(e0);
                }

            bf16x8 pa[2];
            #pragma unroll
            for (int ks2 = 0; ks2 < 2; ++ks2) {
                unsigned a0 = u[2 * ks2][0],     a1 = u[2 * ks2][1];
                unsigned b0 = u[2 * ks2 + 1][0], b1 = u[2 * ks2 + 1][1];
                unsigned a0p = (unsigned)__shfl_xor((int)a0, 32);
                unsigned a1p = (unsigned)__shfl_xor((int)a1, 32);
                unsigned b0p = (unsigned)__shfl_xor((int)b0, 32);
                unsigned b1p = (unsigned)__shfl_xor((int)b1, 32);
                uint4v pw;
                pw.x = hi ? b0p : a0;
                pw.y = hi ? b1p : a1;
                pw.z = hi ? b0  : a0p;
                pw.w = hi ? b1  : a1p;
                pa[ks2] = __builtin_bit_cast(bf16x8, pw);
            }

            #pragma unroll
            for (int dg = 0; dg < 4; ++dg)
                #pragma unroll
                for (int ks2 = 0; ks2 < 2; ++ks2)
                    o[dg] = __builtin_amdgcn_mfma_f32_32x32x16_bf16(tv[dg][ks2], pa[ks2], o[dg], 0, 0, 0);

            __builtin_amdgcn_s_barrier();
            __builtin_amdgcn_sched_barrier(0);
            if (cs + 2 < 16) stage(cs + 2, p);
        }

        __syncthreads();
        float* red = (float*)smem;
        {
            float* base = red + w * 4096;
            #pragma unroll
            for (int dg = 0; dg < 4; ++dg)
                #pragma unroll
                for (int r = 0; r < 16; ++r) {
                    int d = dg * 32 + (r & 3) + 8 * (r >> 2) + 4 * hi;
                    base[d * 32 + la] = o[dg][r];
                }
        }
        __syncthreads();

        {
            int m  = t & 31;
            int dq = t >> 5;
            size_t gbase = ((size_t)(b * L_SEQ + mtile * 32 + m)) * DD + dq * 16;
            #pragma unroll
            for (int jq = 0; jq < 4; ++jq) {
                f32x4 v;
                #pragma unroll
                for (int e = 0; e < 4; ++e) {
                    int idx = (dq * 16 + jq * 4 + e) * 32 + m;
                    v[e] = red[idx] + red[4096 + idx] + red[8192 + idx] + red[12288 + idx];
                }
                f32x4 mv = *(const f32x4*)&mn[gbase + jq * 4];
                f32x4 ov;
                ov[0] = mv[0] - v[0]; ov[1] = mv[1] - v[1];
                ov[2] = mv[2] - v[2]; ov[3] = mv[3] - v[3];
                *(f32x4*)&out[gbase + jq * 4] = ov;
            }
        }
    }
}

// ---------------------------------------------------------------------------
// R12 4-kernel path (used if cooperative launch is rejected)
// ---------------------------------------------------------------------------

__global__ __launch_bounds__(256) void convert_kernel(const float* __restrict__ ctx,
                                                      const float* __restrict__ mn,
                                                      short* __restrict__ Cbf,
                                                      short* __restrict__ Mbf,
                                                      float* __restrict__ Lg) {
    int tid = blockIdx.x * 256 + threadIdx.x;
    if (tid < BATCH * L_SEQ) Lg[tid] = 0.0f;
    const int half = BATCH * L_SEQ * DD / 8;
    int id = tid;
    const float* src;
    short* dst;
    if (id < half) { src = ctx; dst = Cbf; }
    else           { id -= half; src = mn; dst = Mbf; }
    int row = id >> 4;
    int lc = id & 15;
    const float4* p = (const float4*)(src + ((size_t)row << 7) + lc * 8);
    float4 v0 = p[0];
    float4 v1 = p[1];
    bf16x8 s;
    s[0] = f2bf(v0.x); s[1] = f2bf(v0.y); s[2] = f2bf(v0.z); s[3] = f2bf(v0.w);
    s[4] = f2bf(v1.x); s[5] = f2bf(v1.y); s[6] = f2bf(v1.z); s[7] = f2bf(v1.w);
    int pc = (lc & 8) | ((lc ^ row) & 7);
    *(bf16x8*)&dst[((size_t)row << 7) + pc * 8] = s;
}

__global__ __launch_bounds__(256, 2) void stats_kernel(const short* __restrict__ Cbf,
                                                       const short* __restrict__ Mbf,
                                                       float* __restrict__ Lg) {
    __shared__ short Cs[128 * 128];
    __shared__ short Ms[2][64 * 128];

    int bid = blockIdx.x;
    int b  = bid & 7;
    int r2 = bid >> 3;
    int mc = r2 & 3;
    int ct = r2 >> 2;
    int t = threadIdx.x;
    int w = t >> 6;
    int l = t & 63;
    int a15 = l & 15;
    int q = l >> 4;
    int h = a15 & 7;
    int cw = (w & 1) * 64;
    int mw = (w >> 1) * 32;

    const short* gC = Cbf + ((size_t)(b * L_SEQ + ct * 128)) * DD;
    const short* gM = Mbf + ((size_t)(b * L_SEQ + mc * 512)) * DD;

    #pragma unroll
    for (int ii = 0; ii < 8; ++ii) {
        int inst = w * 8 + ii;
        gl2lds16(gC + inst * 512 + l * 8, Cs + inst * 512);
    }
    #pragma unroll
    for (int ii = 0; ii < 4; ++ii) {
        int inst = w * 4 + ii;
        gl2lds16(gM + inst * 512 + l * 8, Ms[0] + inst * 512);
    }
    #pragma unroll
    for (int ii = 0; ii < 4; ++ii) {
        int inst = w * 4 + ii;
        gl2lds16(gM + (size_t)64 * DD + inst * 512 + l * 8, Ms[1] + inst * 512);
    }

    waitv8();
    __builtin_amdgcn_s_barrier();
    __builtin_amdgcn_sched_barrier(0);

    bf16x8 af[4][4];
    #pragma unroll
    for (int ks = 0; ks < 4; ++ks) {
        int aoff = ((ks * 4 + q) ^ h) * 8;
        #pragma unroll
        for (int i = 0; i < 4; ++i)
            af[ks][i] = *(const bf16x8*)&Cs[(cw + i * 16 + a15) * 128 + aoff];
    }

    float ls[4][4] = {};

    for (int ms = 0; ms < 8; ++ms) {
        int bp = ms & 1;
        if (ms < 7) waitv4(); else waitv0();
        __builtin_amdgcn_s_barrier();
        __builtin_amdgcn_sched_barrier(0);

        f32x4 acc[4][2];
        #pragma unroll
        for (int i = 0; i < 4; ++i)
            #pragma unroll
            for (int j = 0; j < 2; ++j) {
                f32x4 z = {0.f, 0.f, 0.f, 0.f};
                acc[i][j] = z;
            }
        #pragma unroll
        for (int ks = 0; ks < 4; ++ks) {
            int aoff = ((ks * 4 + q) ^ h) * 8;
            bf16x8 bv[2];
            #pragma unroll
            for (int j = 0; j < 2; ++j)
                bv[j] = *(const bf16x8*)&Ms[bp][(mw + j * 16 + a15) * 128 + aoff];
            #pragma unroll
            for (int i = 0; i < 4; ++i)
                #pragma unroll
                for (int j = 0; j < 2; ++j)
                    acc[i][j] = __builtin_amdgcn_mfma_f32_16x16x32_bf16(af[ks][i], bv[j], acc[i][j], 0, 0, 0);
        }

        #pragma unroll
        for (int j = 0; j < 2; ++j)
            #pragma unroll
            for (int i = 0; i < 4; ++i)
                #pragma unroll
                for (int r = 0; r < 4; ++r)
                    ls[i][r] += __expf(acc[i][j][r] - SHIFT);

        __builtin_amdgcn_s_barrier();
        __builtin_amdgcn_sched_barrier(0);
        if (ms + 2 < 8) {
            #pragma unroll
            for (int ii = 0; ii < 4; ++ii) {
                int inst = w * 4 + ii;
                gl2lds16(gM + (size_t)(ms + 2) * 64 * DD + inst * 512 + l * 8,
                         Ms[bp] + inst * 512);
            }
        }
    }

    #pragma unroll
    for (int i = 0; i < 4; ++i)
        #pragma unroll
        for (int r = 0; r < 4; ++r) {
            float v = ls[i][r];
            v += __shfl_xor(v, 1);
            v += __shfl_xor(v, 2);
            v += __shfl_xor(v, 4);
            v += __shfl_xor(v, 8);
            ls[i][r] = v;
        }
    if (a15 == 0) {
        #pragma unroll
        for (int i = 0; i < 4; ++i) {
            int c = ct * 128 + cw + i * 16 + q * 4;
            #pragma unroll
            for (int r = 0; r < 4; ++r)
                atomicAdd(&Lg[(size_t)b * L_SEQ + c + r], ls[i][r]);
        }
    }
}

__global__ __launch_bounds__(256) void prep_kernel(const float* __restrict__ ctx,
                                                   const float* __restrict__ Lg,
                                                   short* __restrict__ CtLf) {
    __shared__ short Ts[128 * LDA];
    __shared__ float invLs[128];

    int b = blockIdx.x >> 4;
    int cc = blockIdx.x & 15;
    int t = threadIdx.x;

    if (t < 128) invLs[t] = 1.0f / Lg[(size_t)b * L_SEQ + cc * 128 + t];
    __syncthreads();

    const float* src = ctx + ((size_t)(b * L_SEQ + cc * 128)) * DD;
    #pragma unroll
    for (int i = 0; i < 8; ++i) {
        int flat = i * 2048 + t * 8;
        int r = flat >> 7;
        int c = flat & 127;
        const float4* p = (const float4*)(src + flat);
        float4 v0 = p[0];
        float4 v1 = p[1];
        float il = invLs[r];
        bf16x8 s;
        s[0] = f2bf(v0.x * il); s[1] = f2bf(v0.y * il); s[2] = f2bf(v0.z * il); s[3] = f2bf(v0.w * il);
        s[4] = f2bf(v1.x * il); s[5] = f2bf(v1.y * il); s[6] = f2bf(v1.z * il); s[7] = f2bf(v1.w * il);
        *(bf16x8*)&Ts[r * LDA + c] = s;
    }
    __syncthreads();

    #pragma unroll
    for (int i = 0; i < 8; ++i) {
        int slot = i * 256 + t;
        int rec = slot >> 6;
        int l2  = slot & 63;
        int chh = rec >> 3;
        int dgg = (rec >> 1) & 3;
        int ks2 = rec & 1;
        int la2 = l2 & 31;
        int hi2 = l2 >> 5;
        int d   = dgg * 32 + la2;
        int c0  = (chh * 4 + ks2 * 2 + hi2) * 8;
        bf16x8 v;
        #pragma unroll
        for (int j = 0; j < 8; ++j) v[j] = Ts[(c0 + j) * LDA + d];
        *(bf16x8*)&CtLf[((size_t)(b * 16 + cc) * 32 + rec) * 512 + l2 * 8] = v;
    }
}

__global__ __launch_bounds__(256, 2) void attend_fused(const short* __restrict__ Cbf,
                                                       const short* __restrict__ Mbf,
                                                       const short* __restrict__ CtLf,
                                                       const float* __restrict__ mn,
                                                       float* __restrict__ out) {
    __shared__ __align__(16) char smem[65536];

    int bid = blockIdx.x;
    int b = bid & 7;
    int mtile = bid >> 3;
    int t = threadIdx.x;
    int w = t >> 6;
    int l = t & 63;
    int la = l & 31;
    int hi = l >> 5;
    int ch = w;

    int m_glob = mtile * 32 + la;
    int key7 = la & 7;

    bf16x8 mf[8];
    {
        const short* mrow = Mbf + ((size_t)(b * L_SEQ + m_glob)) * DD;
        #pragma unroll
        for (int ks = 0; ks < 8; ++ks) {
            int lc = ks * 2 + hi;
            int pc = (lc & 8) | ((lc ^ key7) & 7);
            mf[ks] = *(const bf16x8*)&mrow[pc * 8];
        }
    }

    auto stage = [&](int cs, int p) {
        short* Cw = (short*)(smem + p * 32768);
        const short* gC = Cbf + ((size_t)(b * L_SEQ + cs * 128)) * DD;
        #pragma unroll
        for (int ii = 0; ii < 8; ++ii) {
            int inst = w * 8 + ii;
            gl2lds16(gC + inst * 512 + l * 8, Cw + inst * 512);
        }
    };

    f32x16 o[4];
    #pragma unroll
    for (int dg = 0; dg < 4; ++dg)
        #pragma unroll
        for (int r = 0; r < 16; ++r) o[dg][r] = 0.0f;

    stage(0, 0);
    stage(1, 1);

    for (int cs = 0; cs < 16; ++cs) {
        int p = cs & 1;
        waitv8();
        __builtin_amdgcn_s_barrier();
        __builtin_amdgcn_sched_barrier(0);

        const short* gF = CtLf + ((size_t)((b * 16 + cs) * 4 + ch) * 8) * 512 + l * 8;
        bf16x8 tv[4][2];
        #pragma unroll
        for (int dg = 0; dg < 4; ++dg)
            #pragma unroll
            for (int ks2 = 0; ks2 < 2; ++ks2)
                tv[dg][ks2] = *(const bf16x8*)&gF[(dg * 2 + ks2) * 512];

        const short* Cw = (const short*)(smem + p * 32768);

        f32x16 s;
        #pragma unroll
        for (int r = 0; r < 16; ++r) s[r] = 0.0f;
        int crow = ch * 32 + la;
        #pragma unroll
        for (int ks = 0; ks < 8; ++ks) {
            int lc = ks * 2 + hi;
            int pc = (lc & 8) | ((lc ^ key7) & 7);
            bf16x8 av = *(const bf16x8*)&Cw[crow * 128 + pc * 8];
            s = __builtin_amdgcn_mfma_f32_32x32x16_bf16(av, mf[ks], s, 0, 0, 0);
        }

        unsigned u[4][2];
        #pragma unroll
        for (int q = 0; q < 4; ++q)
            #pragma unroll
            for (int jj = 0; jj < 2; ++jj) {
                float e0 = __expf(s[q * 4 + jj * 2]     - SHIFT);
                float e1 = __expf(s[q * 4 + jj * 2 + 1] - SHIFT);
                u[q][jj] = ((unsigned)(unsigned short)f2bf(e1) << 16)
                         |  (unsigned)(unsigned short)f2bf(e0);
            }

        bf16x8 pa[2];
        #pragma unroll
        for (int ks2 = 0; ks2 < 2; ++ks2) {
            unsigned a0 = u[2 * ks2][0],     a1 = u[2 * ks2][1];
            unsigned b0 = u[2 * ks2 + 1][0], b1 = u[2 * ks2 + 1][1];
            unsigned a0p = (unsigned)__shfl_xor((int)a0, 32);
            unsigned a1p = (unsigned)__shfl_xor((int)a1, 32);
            unsigned b0p = (unsigned)__shfl_xor((int)b0, 32);
            unsigned b1p = (unsigned)__shfl_xor((int)b1, 32);
            uint4v pw;
            pw.x = hi ? b0p : a0;
            pw.y = hi ? b1p : a1;
            pw.z = hi ? b0  : a0p;
            pw.w = hi ? b1  : a1p;
            pa[ks2] = __builtin_bit_cast(bf16x8, pw);
        }

        #pragma unroll
        for (int dg = 0; dg < 4; ++dg)
            #pragma unroll
            for (int ks2 = 0; ks2 < 2; ++ks2)
                o[dg] = __builtin_amdgcn_mfma_f32_32x32x16_bf16(tv[dg][ks2], pa[ks2], o[dg], 0, 0, 0);

        __builtin_amdgcn_s_barrier();
        __builtin_amdgcn_sched_barrier(0);
        if (cs + 2 < 16) stage(cs + 2, p);
    }

    __syncthreads();
    float* red = (float*)smem;
    {
        float* base = red + w * 4096;
        #pragma unroll
        for (int dg = 0; dg < 4; ++dg)
            #pragma unroll
            for (int r = 0; r < 16; ++r) {
                int d = dg * 32 + (r & 3) + 8 * (r >> 2) + 4 * hi;
                base[d * 32 + la] = o[dg][r];
            }
    }
    __syncthreads();

    {
        int m  = t & 31;
        int dq = t >> 5;
        size_t gbase = ((size_t)(b * L_SEQ + mtile * 32 + m)) * DD + dq * 16;
        #pragma unroll
        for (int jq = 0; jq < 4; ++jq) {
            f32x4 v;
            #pragma unroll
            for (int e = 0; e < 4; ++e) {
                int idx = (dq * 16 + jq * 4 + e) * 32 + m;
                v[e] = red[idx] + red[4096 + idx] + red[8192 + idx] + red[12288 + idx];
            }
            f32x4 mv = *(const f32x4*)&mn[gbase + jq * 4];
            f32x4 ov;
            ov[0] = mv[0] - v[0]; ov[1] = mv[1] - v[1];
            ov[2] = mv[2] - v[2]; ov[3] = mv[3] - v[3];
            *(f32x4*)&out[gbase + jq * 4] = ov;
        }
    }
}

// ---------------------------------------------------------------------------
// Fallback path (round-2 kernels, tiny workspace)
// ---------------------------------------------------------------------------

__global__ __launch_bounds__(256, 4) void stats_fb(const float* __restrict__ ctx,
                                                   const float* __restrict__ mn,
                                                   float* __restrict__ Lg) {
    __shared__ short Cs[64 * LDA];
    __shared__ short Ms[64 * LDA];

    int bid = blockIdx.x;
    int mc = bid & 3;
    int ct = (bid >> 2) & 31;
    int b  = bid >> 7;
    int t = threadIdx.x;
    int w = t >> 6;
    int l = t & 63;
    int a15 = l & 15;
    int q = l >> 4;

    stage_tile<256>(Cs, ctx + ((size_t)b * L_SEQ + ct * 64) * DD, 64 * DD, t);

    float ls[4] = {0.f, 0.f, 0.f, 0.f};
    for (int mt = 0; mt < 8; ++mt) {
        __syncthreads();
        int m0 = (mc * 8 + mt) * 64;
        stage_tile<256>(Ms, mn + ((size_t)b * L_SEQ + m0) * DD, 64 * DD, t);
        __syncthreads();

        f32x4 acc[4] = {{0.f,0.f,0.f,0.f},{0.f,0.f,0.f,0.f},{0.f,0.f,0.f,0.f},{0.f,0.f,0.f,0.f}};
        #pragma unroll
        for (int ks = 0; ks < 4; ++ks) {
            int k0 = ks * 32 + q * 8;
            bf16x8 a = *(const bf16x8*)&Cs[(w * 16 + a15) * LDA + k0];
            #pragma unroll
            for (int g = 0; g < 4; ++g) {
                bf16x8 bb = *(const bf16x8*)&Ms[(g * 16 + a15) * LDA + k0];
                acc[g] = __builtin_amdgcn_mfma_f32_16x16x32_bf16(a, bb, acc[g], 0, 0, 0);
            }
        }
        #pragma unroll
        for (int g = 0; g < 4; ++g)
            #pragma unroll
            for (int r = 0; r < 4; ++r)
                ls[r] += __expf(acc[g][r] - SHIFT);
    }

    #pragma unroll
    for (int r = 0; r < 4; ++r) {
        float v = ls[r];
        v += __shfl_xor(v, 1);
        v += __shfl_xor(v, 2);
        v += __shfl_xor(v, 4);
        v += __shfl_xor(v, 8);
        ls[r] = v;
    }
    if (a15 == 0) {
        int c = ct * 64 + w * 16 + q * 4;
        #pragma unroll
        for (int r = 0; r < 4; ++r)
            atomicAdd(&Lg[(size_t)b * L_SEQ + c + r], ls[r]);
    }
}

__global__ __launch_bounds__(1024, 4) void attend_fb(const float* __restrict__ ctx,
                                                     const float* __restrict__ mn,
                                                     const float* __restrict__ Lg,
                                                     float* __restrict__ out) {
    __shared__ short Mt[64 * LDA];
    __shared__ short Cs[128 * LDA];
    __shared__ short Ct[128 * LDA];
    __shared__ short Ps[64 * LDA];
    __shared__ float invLs[128];

    int bid = blockIdx.x;
    int mtile = bid & 31;
    int b = bid >> 5;
    int m0 = mtile * 64;
    int t = threadIdx.x;
    int w = t >> 6;
    int l = t & 63;
    int a15 = l & 15;
    int q = l >> 4;
    int mg = w & 3;
    int pg = w >> 2;

    stage_tile<1024>(Mt, mn + ((size_t)b * L_SEQ + m0) * DD, 64 * DD, t);

    f32x4 oacc[2] = {{0.f,0.f,0.f,0.f},{0.f,0.f,0.f,0.f}};

    for (int cs = 0; cs < 16; ++cs) {
        int c0 = cs * 128;
        __syncthreads();
        stage_tile<1024>(Cs, ctx + ((size_t)b * L_SEQ + c0) * DD, 128 * DD, t);
        if (t < 128) invLs[t] = 1.0f / Lg[(size_t)b * L_SEQ + c0 + t];
        __syncthreads();

        {
            int cc = t & 127;
            int d0 = (t >> 7) * 16;
            #pragma unroll
            for (int hh = 0; hh < 2; ++hh) {
                bf16x8 v = *(const bf16x8*)&Cs[cc * LDA + d0 + hh * 8];
                #pragma unroll
                for (int j = 0; j < 8; ++j)
                    Ct[(d0 + hh * 8 + j) * LDA + cc] = v[j];
            }
        }

        f32x4 sacc[2] = {{0.f,0.f,0.f,0.f},{0.f,0.f,0.f,0.f}};
        #pragma unroll
        for (int ks = 0; ks < 4; ++ks) {
            int k0 = ks * 32 + q * 8;
            bf16x8 a = *(const bf16x8*)&Mt[(mg * 16 + a15) * LDA + k0];
            #pragma unroll
            for (int g = 0; g < 2; ++g) {
                bf16x8 bb = *(const bf16x8*)&Cs[((pg * 2 + g) * 16 + a15) * LDA + k0];
                sacc[g] = __builtin_amdgcn_mfma_f32_16x16x32_bf16(a, bb, sacc[g], 0, 0, 0);
            }
        }
        #pragma unroll
        for (int g = 0; g < 2; ++g) {
            int cl = (pg * 2 + g) * 16 + a15;
            float il = invLs[cl];
            #pragma unroll
            for (int r = 0; r < 4; ++r) {
                float p = __expf(sacc[g][r] - SHIFT) * il;
                Ps[(mg * 16 + q * 4 + r) * LDA + cl] = f2bf(p);
            }
        }
        __syncthreads();

        #pragma unroll
        for (int ks = 0; ks < 4; ++ks) {
            int k0 = ks * 32 + q * 8;
            bf16x8 a = *(const bf16x8*)&Ps[(mg * 16 + a15) * LDA + k0];
            #pragma unroll
            for (int g = 0; g < 2; ++g) {
                bf16x8 bb = *(const bf16x8*)&Ct[((pg * 2 + g) * 16 + a15) * LDA + k0];
                oacc[g] = __builtin_amdgcn_mfma_f32_16x16x32_bf16(a, bb, oacc[g], 0, 0, 0);
            }
        }
    }

    #pragma unroll
    for (int g = 0; g < 2; ++g) {
        int dl = (pg * 2 + g) * 16 + a15;
        #pragma unroll
        for (int r = 0; r < 4; ++r) {
            int ml = mg * 16 + q * 4 + r;
            size_t idx = ((size_t)b * L_SEQ + m0 + ml) * DD + dl;
            out[idx] = mn[idx] - oacc[g][r];
        }
    }
}

// ---------------------------------------------------------------------------

extern "C" void kernel_launch(void* const* d_in, const int* in_sizes, int n_in,
                              void* d_out, int out_size, void* d_ws, size_t ws_size,
                              hipStream_t stream) {
    const float* ctx = (const float*)d_in[0];  // (B, Lc, D)
    const float* mn  = (const float*)d_in[1];  // (B, Lm, D)
    float* out = (float*)d_out;                // (B, Lm, D)

    // Workspace: Lg 64 KB | Cbf 4 MB | Mbf 4 MB | CtLf 4 MB
    const size_t LG_BYTES = (size_t)BATCH * L_SEQ * sizeof(float);
    const size_t BF_BYTES = (size_t)BATCH * L_SEQ * DD * sizeof(short);
    const size_t NEED = LG_BYTES + 3 * BF_BYTES;

    float* Lg = (float*)d_ws;

    if (ws_size >= NEED) {
        short* Cbf  = (short*)((char*)d_ws + LG_BYTES);
        short* Mbf  = (short*)((char*)d_ws + LG_BYTES + BF_BYTES);
        short* CtLf = (short*)((char*)d_ws + LG_BYTES + 2 * BF_BYTES);

        void* args[] = {(void*)&ctx, (void*)&mn, (void*)&Cbf, (void*)&Mbf,
                        (void*)&CtLf, (void*)&Lg, (void*)&out};
        hipError_t err = hipLaunchCooperativeKernel(
            reinterpret_cast<void*>(mega_kernel), dim3(512), dim3(256),
            args, 0, stream);
        if (err != hipSuccess) {
            // Cooperative rejected (e.g. capture mode): R12 4-kernel path.
            convert_kernel<<<2048, 256, 0, stream>>>(ctx, mn, Cbf, Mbf, Lg);
            stats_kernel<<<BATCH * 16 * 4, 256, 0, stream>>>(Cbf, Mbf, Lg);
            prep_kernel<<<BATCH * 16, 256, 0, stream>>>(ctx, Lg, CtLf);
            attend_fused<<<BATCH * 64, 256, 0, stream>>>(Cbf, Mbf, CtLf, mn, out);
        }
    } else {
        int nL = BATCH * L_SEQ;
        zero_kernel<<<(nL + 255) / 256, 256, 0, stream>>>(Lg, nL);
        stats_fb<<<BATCH * 32 * 4, 256, 0, stream>>>(ctx, mn, Lg);
        attend_fb<<<BATCH * 32, 1024, 0, stream>>>(ctx, mn, Lg, out);
    }
}

// Round 7
// 121.419 us; speedup vs baseline: 2.3013x; 2.3013x over previous
//
#include <hip/hip_runtime.h>

// AlignOnlySubLayer: out[b,m,d] = main[b,m,d] - sum_c softmax_m(C·M^T)[c,m] * C[c,d]
// B=8, Lc=Lm=2048, D=128, fp32 in/out.
// Round-16: ALL-fragment-record pipeline, 3 barrier-free kernels.
// R15 mega measured 66 us fixed harness overhead => R12's 4 kernels were only
// ~55 us GPU. This round removes every main-loop barrier and every LDS staging
// path by making EVERY MFMA operand a coalesced 1KB fragment record
// (lane l reads bytes [l*16, l*16+16) — one wave-load per fragment):
//   convert: LDS-bounce 32-row tiles -> emit Cf / Mf / Ctf records (no /L!)
//   stats  : swapped mfma(Mf,Cf) puts c in the lane column -> L[c] accumulates
//            in ONE register across all m; 1 shfl + tiny LDS; writes invL.
//            No atomics, no staging, no barriers.
//   attend : R12 body, operands av=Cf, mf=Mf, tv=Ctf (all records), invL
//            multiplied into P before pack (4 broadcast float4 / window).
//            No barriers until the epilogue reduction.
// Record layouts (la=l&31, hi=l>>5, e=0..7):
//   Cf [((b*16+cs)*4+ch)*8+ks]          lane l = C[cs*128+ch*32+la][(ks*2+hi)*8+e]
//   Mf [(b*64+mw)*8+ks]                 lane l = M[mw*32+la][(ks*2+hi)*8+e]
//   Ctf[(((b*16+cs)*4+ch)*4+dg)*2+ks2]  lane l = C[cs*128+(ch*4+ks2*2+hi)*8+e][dg*32+la]
// MFMA frag layout (32x32x16, verified R9-R12): A/B lane (la,hi) holds
// row/col la, k = hi*8+e; D: col=la, row=(r&3)+8*(r>>2)+4*hi.

#define BATCH 8
#define L_SEQ 2048
#define DD 128
#define SHIFT 40.0f
#define LDA 136   // fallback padded stride
#define TLD 136   // convert LDS tile stride (shorts)

typedef __attribute__((ext_vector_type(8))) short bf16x8;
typedef __attribute__((ext_vector_type(4))) float f32x4;
typedef __attribute__((ext_vector_type(16))) float f32x16;
typedef __attribute__((ext_vector_type(4))) unsigned int uint4v;

__device__ __forceinline__ short f2bf(float f) {
    unsigned u = __builtin_bit_cast(unsigned, f);
    return (short)((u + 0x8000u) >> 16);
}

// fp32 global (rows of 128) -> bf16 LDS tile, stride LDA (fallback path only).
template <int NT>
__device__ __forceinline__ void stage_tile(short* __restrict__ dst,
                                           const float* __restrict__ src,
                                           int nelts, int t) {
    for (int base = 0; base < nelts; base += NT * 8) {
        int flat = base + t * 8;
        const float4* p = (const float4*)(src + flat);
        float4 v0 = p[0];
        float4 v1 = p[1];
        bf16x8 s;
        s[0] = f2bf(v0.x); s[1] = f2bf(v0.y); s[2] = f2bf(v0.z); s[3] = f2bf(v0.w);
        s[4] = f2bf(v1.x); s[5] = f2bf(v1.y); s[6] = f2bf(v1.z); s[7] = f2bf(v1.w);
        int row = flat >> 7;
        int col = flat & 127;
        *(bf16x8*)&dst[row * LDA + col] = s;
    }
}

__global__ __launch_bounds__(256) void zero_kernel(float* __restrict__ p, int n) {
    int i = blockIdx.x * 256 + threadIdx.x;
    if (i < n) p[i] = 0.0f;
}

// ---------------------------------------------------------------------------
// Fast path
// ---------------------------------------------------------------------------

// grid = 2 tensors x 8 b x 64 rowgroups = 1024 blocks, 256 thr.
// Stages a 32-row fp32 tile -> bf16 LDS, then emits fragment records.
__global__ __launch_bounds__(256) void convert_kernel(const float* __restrict__ ctx,
                                                      const float* __restrict__ mn,
                                                      short* __restrict__ Cf,
                                                      short* __restrict__ Mf,
                                                      short* __restrict__ Ctf) {
    __shared__ short Ts[32 * TLD];

    int bid = blockIdx.x;
    int tsel = bid & 1;
    int b = (bid >> 1) & 7;
    int rg = bid >> 4;          // 0..63 : 32-row group
    int t = threadIdx.x;

    const float* src = (tsel ? mn : ctx) + ((size_t)(b * L_SEQ + rg * 32)) * DD;

    #pragma unroll
    for (int i = 0; i < 2; ++i) {
        int flat = i * 2048 + t * 8;
        int r = flat >> 7;
        int d = flat & 127;
        const float4* p = (const float4*)(src + flat);
        float4 v0 = p[0];
        float4 v1 = p[1];
        bf16x8 s;
        s[0] = f2bf(v0.x); s[1] = f2bf(v0.y); s[2] = f2bf(v0.z); s[3] = f2bf(v0.w);
        s[4] = f2bf(v1.x); s[5] = f2bf(v1.y); s[6] = f2bf(v1.z); s[7] = f2bf(v1.w);
        *(bf16x8*)&Ts[r * TLD + d] = s;
    }
    __syncthreads();

    if (tsel == 0) {
        int cs = rg >> 2;
        int ch = rg & 3;
        // Cf: 8 records (ks), 64 lane-slots each; 2 slots/thread.
        size_t cfb = (size_t)(((b * 16 + cs) * 4 + ch) * 8) * 512;
        #pragma unroll
        for (int i = 0; i < 2; ++i) {
            int slot = i * 256 + t;
            int ks = slot >> 6;
            int l2 = slot & 63;
            int la = l2 & 31;
            int hi = l2 >> 5;
            bf16x8 v = *(const bf16x8*)&Ts[la * TLD + (ks * 2 + hi) * 8];
            *(bf16x8*)&Cf[cfb + (size_t)ks * 512 + l2 * 8] = v;
        }
        // Ctf: 8 records (dg,ks2); transpose gather from LDS.
        size_t ctb = (size_t)((((b * 16 + cs) * 4 + ch) * 4) * 2) * 512;
        #pragma unroll
        for (int i = 0; i < 2; ++i) {
            int slot = i * 256 + t;
            int recl = slot >> 6;       // dg*2 + ks2
            int l2 = slot & 63;
            int dg = recl >> 1;
            int ks2 = recl & 1;
            int la = l2 & 31;
            int hi = l2 >> 5;
            int d = dg * 32 + la;
            int c0 = (ks2 * 2 + hi) * 8;     // local c row base
            bf16x8 v;
            #pragma unroll
            for (int j = 0; j < 8; ++j) v[j] = Ts[(c0 + j) * TLD + d];
            *(bf16x8*)&Ctf[ctb + (size_t)recl * 512 + l2 * 8] = v;
        }
    } else {
        // Mf: 8 records (ks); rowgroup rg = mw.
        size_t mfb = (size_t)((b * 64 + rg) * 8) * 512;
        #pragma unroll
        for (int i = 0; i < 2; ++i) {
            int slot = i * 256 + t;
            int ks = slot >> 6;
            int l2 = slot & 63;
            int la = l2 & 31;
            int hi = l2 >> 5;
            bf16x8 v = *(const bf16x8*)&Ts[la * TLD + (ks * 2 + hi) * 8];
            *(bf16x8*)&Mf[mfb + (size_t)ks * 512 + l2 * 8] = v;
        }
    }
}

// grid = 8 b x 64 ctiles(32 c) = 512 blocks (b = bid&7), 256 thr (4 waves).
// Swapped S: D[i=m][j=c=la] = mfma(Mf, Cf) -> L[c] accumulates in ONE register
// per lane across all m. No staging, no barriers, no atomics. Writes invL.
__global__ __launch_bounds__(256) void stats_kernel(const short* __restrict__ Cf,
                                                    const short* __restrict__ Mf,
                                                    float* __restrict__ invLg) {
    __shared__ float red[4][32];

    int bid = blockIdx.x;
    int b = bid & 7;
    int ct = bid >> 3;          // 0..63 : 32-c tile
    int t = threadIdx.x;
    int w = t >> 6;
    int l = t & 63;
    int la = l & 31;

    // Hoist C B-frags for c = ct*32 + la  (Cf record (cs=ct>>2, ch=ct&3, ks)).
    bf16x8 cf[8];
    {
        const short* cfp = Cf + (size_t)(((b * 16 + (ct >> 2)) * 4 + (ct & 3)) * 8) * 512 + l * 8;
        #pragma unroll
        for (int ks = 0; ks < 8; ++ks)
            cf[ks] = *(const bf16x8*)&cfp[(size_t)ks * 512];
    }

    float lacc = 0.0f;
    for (int mw = w * 16; mw < w * 16 + 16; ++mw) {
        const short* mfp = Mf + (size_t)((b * 64 + mw) * 8) * 512 + l * 8;
        f32x16 s;
        #pragma unroll
        for (int r = 0; r < 16; ++r) s[r] = 0.0f;
        #pragma unroll
        for (int ks = 0; ks < 8; ++ks) {
            bf16x8 av = *(const bf16x8*)&mfp[(size_t)ks * 512];
            s = __builtin_amdgcn_mfma_f32_32x32x16_bf16(av, cf[ks], s, 0, 0, 0);
        }
        #pragma unroll
        for (int r = 0; r < 16; ++r)
            lacc += __expf(s[r] - SHIFT);
    }

    // hi halves hold disjoint m-subsets of the same c=la: combine, reduce waves.
    lacc += __shfl_xor(lacc, 32);
    if (l < 32) red[w][la] = lacc;
    __syncthreads();
    if (t < 32) {
        float L = red[0][t] + red[1][t] + red[2][t] + red[3][t];
        invLg[(size_t)b * L_SEQ + ct * 32 + t] = 1.0f / L;
    }
}

// grid = 8 b x 64 mtiles(32 m) = 512 blocks (b = bid&7), 256 thr = 4 waves
// (4 c-slices). ALL operands are coalesced records; NO barriers in the main
// loop. LDS 64 KB only for the epilogue cross-slice reduction (2 blocks/CU).
__global__ __launch_bounds__(256, 2) void attend_fused(const short* __restrict__ Cf,
                                                       const short* __restrict__ Mf,
                                                       const short* __restrict__ Ctf,
                                                       const float* __restrict__ invLg,
                                                       const float* __restrict__ mn,
                                                       float* __restrict__ out) {
    __shared__ float red[4][4096];

    int bid = blockIdx.x;
    int b = bid & 7;
    int mtile = bid >> 3;       // 0..63
    int t = threadIdx.x;
    int w = t >> 6;             // ch
    int l = t & 63;
    int la = l & 31;
    int hi = l >> 5;
    int ch = w;

    // Hoist M B-frags from Mf record (mw = mtile) — same records stats read.
    bf16x8 mf[8];
    {
        const short* mfp = Mf + (size_t)((b * 64 + mtile) * 8) * 512 + l * 8;
        #pragma unroll
        for (int ks = 0; ks < 8; ++ks)
            mf[ks] = *(const bf16x8*)&mfp[(size_t)ks * 512];
    }

    f32x16 o[4];
    #pragma unroll
    for (int dg = 0; dg < 4; ++dg)
        #pragma unroll
        for (int r = 0; r < 16; ++r) o[dg][r] = 0.0f;

    const float* ilbase = invLg + (size_t)b * L_SEQ + ch * 32 + hi * 4;

    for (int cs = 0; cs < 16; ++cs) {
        const short* cfp = Cf + (size_t)(((b * 16 + cs) * 4 + ch) * 8) * 512 + l * 8;
        const short* tfp = Ctf + (size_t)((((b * 16 + cs) * 4 + ch) * 4) * 2) * 512 + l * 8;

        // PV A-frags: 8 coalesced record loads (independent of S, fly early).
        bf16x8 tv[4][2];
        #pragma unroll
        for (int dg = 0; dg < 4; ++dg)
            #pragma unroll
            for (int ks2 = 0; ks2 < 2; ++ks2)
                tv[dg][ks2] = *(const bf16x8*)&tfp[(size_t)(dg * 2 + ks2) * 512];

        // invL for this window's 16 c's per lane (broadcast float4 loads).
        f32x4 ilv[4];
        #pragma unroll
        for (int q = 0; q < 4; ++q)
            ilv[q] = *(const f32x4*)&ilbase[cs * 128 + q * 8];

        // S-GEMM (swapped): D[i=c][j=m=la], A = Cf records.
        f32x16 s;
        #pragma unroll
        for (int r = 0; r < 16; ++r) s[r] = 0.0f;
        #pragma unroll
        for (int ks = 0; ks < 8; ++ks) {
            bf16x8 av = *(const bf16x8*)&cfp[(size_t)ks * 512];
            s = __builtin_amdgcn_mfma_f32_32x32x16_bf16(av, mf[ks], s, 0, 0, 0);
        }

        // P = exp(S-40) * invL[c] -> bf16 pairs. reg r=q*4+sub: c_local = sub+8q+4hi.
        unsigned u[4][2];
        #pragma unroll
        for (int q = 0; q < 4; ++q)
            #pragma unroll
            for (int jj = 0; jj < 2; ++jj) {
                float e0 = __expf(s[q * 4 + jj * 2]     - SHIFT) * ilv[q][jj * 2];
                float e1 = __expf(s[q * 4 + jj * 2 + 1] - SHIFT) * ilv[q][jj * 2 + 1];
                u[q][jj] = ((unsigned)(unsigned short)f2bf(e1) << 16)
                         |  (unsigned)(unsigned short)f2bf(e0);
            }

        // Half-wave exchange -> PV B-frags (c_local = ks2*16 + hi*8 + 0..7).
        bf16x8 pa[2];
        #pragma unroll
        for (int ks2 = 0; ks2 < 2; ++ks2) {
            unsigned a0 = u[2 * ks2][0],     a1 = u[2 * ks2][1];
            unsigned b0 = u[2 * ks2 + 1][0], b1 = u[2 * ks2 + 1][1];
            unsigned a0p = (unsigned)__shfl_xor((int)a0, 32);
            unsigned a1p = (unsigned)__shfl_xor((int)a1, 32);
            unsigned b0p = (unsigned)__shfl_xor((int)b0, 32);
            unsigned b1p = (unsigned)__shfl_xor((int)b1, 32);
            uint4v pw;
            pw.x = hi ? b0p : a0;
            pw.y = hi ? b1p : a1;
            pw.z = hi ? b0  : a0p;
            pw.w = hi ? b1  : a1p;
            pa[ks2] = __builtin_bit_cast(bf16x8, pw);
        }

        // PV: D2[i=d][j=m], A = tv (Ctf records), B = pa.
        #pragma unroll
        for (int dg = 0; dg < 4; ++dg)
            #pragma unroll
            for (int ks2 = 0; ks2 < 2; ++ks2)
                o[dg] = __builtin_amdgcn_mfma_f32_32x32x16_bf16(tv[dg][ks2], pa[ks2], o[dg], 0, 0, 0);
    }

    // Epilogue: per-wave partials -> LDS, sum 4 c-slices, out = main - sum.
    {
        float* base = red[w];
        #pragma unroll
        for (int dg = 0; dg < 4; ++dg)
            #pragma unroll
            for (int r = 0; r < 16; ++r) {
                int d = dg * 32 + (r & 3) + 8 * (r >> 2) + 4 * hi;
                base[d * 32 + la] = o[dg][r];
            }
    }
    __syncthreads();

    {
        int m  = t & 31;
        int dq = t >> 5;
        size_t gbase = ((size_t)(b * L_SEQ + mtile * 32 + m)) * DD + dq * 16;
        #pragma unroll
        for (int jq = 0; jq < 4; ++jq) {
            f32x4 v;
            #pragma unroll
            for (int e = 0; e < 4; ++e) {
                int idx = (dq * 16 + jq * 4 + e) * 32 + m;
                v[e] = red[0][idx] + red[1][idx] + red[2][idx] + red[3][idx];
            }
            f32x4 mv = *(const f32x4*)&mn[gbase + jq * 4];
            f32x4 ov;
            ov[0] = mv[0] - v[0]; ov[1] = mv[1] - v[1];
            ov[2] = mv[2] - v[2]; ov[3] = mv[3] - v[3];
            *(f32x4*)&out[gbase + jq * 4] = ov;
        }
    }
}

// ---------------------------------------------------------------------------
// Fallback path (round-2 kernels, tiny workspace)
// ---------------------------------------------------------------------------

__global__ __launch_bounds__(256, 4) void stats_fb(const float* __restrict__ ctx,
                                                   const float* __restrict__ mn,
                                                   float* __restrict__ Lg) {
    __shared__ short Cs[64 * LDA];
    __shared__ short Ms[64 * LDA];

    int bid = blockIdx.x;
    int mc = bid & 3;
    int ct = (bid >> 2) & 31;
    int b  = bid >> 7;
    int t = threadIdx.x;
    int w = t >> 6;
    int l = t & 63;
    int a15 = l & 15;
    int q = l >> 4;

    stage_tile<256>(Cs, ctx + ((size_t)b * L_SEQ + ct * 64) * DD, 64 * DD, t);

    float ls[4] = {0.f, 0.f, 0.f, 0.f};
    for (int mt = 0; mt < 8; ++mt) {
        __syncthreads();
        int m0 = (mc * 8 + mt) * 64;
        stage_tile<256>(Ms, mn + ((size_t)b * L_SEQ + m0) * DD, 64 * DD, t);
        __syncthreads();

        f32x4 acc[4] = {{0.f,0.f,0.f,0.f},{0.f,0.f,0.f,0.f},{0.f,0.f,0.f,0.f},{0.f,0.f,0.f,0.f}};
        #pragma unroll
        for (int ks = 0; ks < 4; ++ks) {
            int k0 = ks * 32 + q * 8;
            bf16x8 a = *(const bf16x8*)&Cs[(w * 16 + a15) * LDA + k0];
            #pragma unroll
            for (int g = 0; g < 4; ++g) {
                bf16x8 bb = *(const bf16x8*)&Ms[(g * 16 + a15) * LDA + k0];
                acc[g] = __builtin_amdgcn_mfma_f32_16x16x32_bf16(a, bb, acc[g], 0, 0, 0);
            }
        }
        #pragma unroll
        for (int g = 0; g < 4; ++g)
            #pragma unroll
            for (int r = 0; r < 4; ++r)
                ls[r] += __expf(acc[g][r] - SHIFT);
    }

    #pragma unroll
    for (int r = 0; r < 4; ++r) {
        float v = ls[r];
        v += __shfl_xor(v, 1);
        v += __shfl_xor(v, 2);
        v += __shfl_xor(v, 4);
        v += __shfl_xor(v, 8);
        ls[r] = v;
    }
    if (a15 == 0) {
        int c = ct * 64 + w * 16 + q * 4;
        #pragma unroll
        for (int r = 0; r < 4; ++r)
            atomicAdd(&Lg[(size_t)b * L_SEQ + c + r], ls[r]);
    }
}

__global__ __launch_bounds__(1024, 4) void attend_fb(const float* __restrict__ ctx,
                                                     const float* __restrict__ mn,
                                                     const float* __restrict__ Lg,
                                                     float* __restrict__ out) {
    __shared__ short Mt[64 * LDA];
    __shared__ short Cs[128 * LDA];
    __shared__ short Ct[128 * LDA];
    __shared__ short Ps[64 * LDA];
    __shared__ float invLs[128];

    int bid = blockIdx.x;
    int mtile = bid & 31;
    int b = bid >> 5;
    int m0 = mtile * 64;
    int t = threadIdx.x;
    int w = t >> 6;
    int l = t & 63;
    int a15 = l & 15;
    int q = l >> 4;
    int mg = w & 3;
    int pg = w >> 2;

    stage_tile<1024>(Mt, mn + ((size_t)b * L_SEQ + m0) * DD, 64 * DD, t);

    f32x4 oacc[2] = {{0.f,0.f,0.f,0.f},{0.f,0.f,0.f,0.f}};

    for (int cs = 0; cs < 16; ++cs) {
        int c0 = cs * 128;
        __syncthreads();
        stage_tile<1024>(Cs, ctx + ((size_t)b * L_SEQ + c0) * DD, 128 * DD, t);
        if (t < 128) invLs[t] = 1.0f / Lg[(size_t)b * L_SEQ + c0 + t];
        __syncthreads();

        {
            int cc = t & 127;
            int d0 = (t >> 7) * 16;
            #pragma unroll
            for (int hh = 0; hh < 2; ++hh) {
                bf16x8 v = *(const bf16x8*)&Cs[cc * LDA + d0 + hh * 8];
                #pragma unroll
                for (int j = 0; j < 8; ++j)
                    Ct[(d0 + hh * 8 + j) * LDA + cc] = v[j];
            }
        }

        f32x4 sacc[2] = {{0.f,0.f,0.f,0.f},{0.f,0.f,0.f,0.f}};
        #pragma unroll
        for (int ks = 0; ks < 4; ++ks) {
            int k0 = ks * 32 + q * 8;
            bf16x8 a = *(const bf16x8*)&Mt[(mg * 16 + a15) * LDA + k0];
            #pragma unroll
            for (int g = 0; g < 2; ++g) {
                bf16x8 bb = *(const bf16x8*)&Cs[((pg * 2 + g) * 16 + a15) * LDA + k0];
                sacc[g] = __builtin_amdgcn_mfma_f32_16x16x32_bf16(a, bb, sacc[g], 0, 0, 0);
            }
        }
        #pragma unroll
        for (int g = 0; g < 2; ++g) {
            int cl = (pg * 2 + g) * 16 + a15;
            float il = invLs[cl];
            #pragma unroll
            for (int r = 0; r < 4; ++r) {
                float p = __expf(sacc[g][r] - SHIFT) * il;
                Ps[(mg * 16 + q * 4 + r) * LDA + cl] = f2bf(p);
            }
        }
        __syncthreads();

        #pragma unroll
        for (int ks = 0; ks < 4; ++ks) {
            int k0 = ks * 32 + q * 8;
            bf16x8 a = *(const bf16x8*)&Ps[(mg * 16 + a15) * LDA + k0];
            #pragma unroll
            for (int g = 0; g < 2; ++g) {
                bf16x8 bb = *(const bf16x8*)&Ct[((pg * 2 + g) * 16 + a15) * LDA + k0];
                oacc[g] = __builtin_amdgcn_mfma_f32_16x16x32_bf16(a, bb, oacc[g], 0, 0, 0);
            }
        }
    }

    #pragma unroll
    for (int g = 0; g < 2; ++g) {
        int dl = (pg * 2 + g) * 16 + a15;
        #pragma unroll
        for (int r = 0; r < 4; ++r) {
            int ml = mg * 16 + q * 4 + r;
            size_t idx = ((size_t)b * L_SEQ + m0 + ml) * DD + dl;
            out[idx] = mn[idx] - oacc[g][r];
        }
    }
}

// ---------------------------------------------------------------------------

extern "C" void kernel_launch(void* const* d_in, const int* in_sizes, int n_in,
                              void* d_out, int out_size, void* d_ws, size_t ws_size,
                              hipStream_t stream) {
    const float* ctx = (const float*)d_in[0];  // (B, Lc, D)
    const float* mn  = (const float*)d_in[1];  // (B, Lm, D)
    float* out = (float*)d_out;                // (B, Lm, D)

    // Workspace: invLg 64 KB | Cf 4 MB | Mf 4 MB | Ctf 4 MB
    const size_t LG_BYTES = (size_t)BATCH * L_SEQ * sizeof(float);
    const size_t BF_BYTES = (size_t)BATCH * L_SEQ * DD * sizeof(short);
    const size_t NEED = LG_BYTES + 3 * BF_BYTES;

    float* Lg = (float*)d_ws;

    if (ws_size >= NEED) {
        short* Cf  = (short*)((char*)d_ws + LG_BYTES);
        short* Mf  = (short*)((char*)d_ws + LG_BYTES + BF_BYTES);
        short* Ctf = (short*)((char*)d_ws + LG_BYTES + 2 * BF_BYTES);
        convert_kernel<<<1024, 256, 0, stream>>>(ctx, mn, Cf, Mf, Ctf);
        stats_kernel<<<512, 256, 0, stream>>>(Cf, Mf, Lg);
        attend_fused<<<512, 256, 0, stream>>>(Cf, Mf, Ctf, Lg, mn, out);
    } else {
        int nL = BATCH * L_SEQ;
        zero_kernel<<<(nL + 255) / 256, 256, 0, stream>>>(Lg, nL);
        stats_fb<<<BATCH * 32 * 4, 256, 0, stream>>>(ctx, mn, Lg);
        attend_fb<<<BATCH * 32, 1024, 0, stream>>>(ctx, mn, Lg, out);
    }
}

// Round 8
// 113.803 us; speedup vs baseline: 2.4553x; 1.0669x over previous
//
#include <hip/hip_runtime.h>

// AlignOnlySubLayer: out[b,m,d] = main[b,m,d] - sum_c softmax_m(C·M^T)[c,m] * C[c,d]
// B=8, Lc=Lm=2048, D=128, fp32 in/out.
// Round-17: stats c-tile 64 + dual MFMA chains. R16 analysis: attend's L2
// traffic is irreducible at m-tile 32 (no intra-block duplication remains);
// stats' 256 MB Mf re-read (512 blocks x full panel) + single-chain MFMA is
// the largest reducible term. stats v3: 256 blocks x 512 thr (8 waves,
// 1 block/CU = 2 waves/SIMD, same occupancy), cf[2][8] hoisted (64-c tile),
// TWO independent accumulator chains per Mf load -> Mf traffic 256->128 MB
// and 2x MFMA ILP. No atomics, no staging; writes invL directly.
// convert/attend: R16 bodies verbatim.
// Record layouts (la=l&31, hi=l>>5, e=0..7):
//   Cf [((b*16+cs)*4+ch)*8+ks]          lane l = C[cs*128+ch*32+la][(ks*2+hi)*8+e]
//   Mf [(b*64+mw)*8+ks]                 lane l = M[mw*32+la][(ks*2+hi)*8+e]
//   Ctf[(((b*16+cs)*4+ch)*4+dg)*2+ks2]  lane l = C[cs*128+(ch*4+ks2*2+hi)*8+e][dg*32+la]
// MFMA frag layout (32x32x16, verified R9-R16): A/B lane (la,hi) holds
// row/col la, k = hi*8+e; D: col=la, row=(r&3)+8*(r>>2)+4*hi.

#define BATCH 8
#define L_SEQ 2048
#define DD 128
#define SHIFT 40.0f
#define LDA 136   // fallback padded stride
#define TLD 136   // convert LDS tile stride (shorts)

typedef __attribute__((ext_vector_type(8))) short bf16x8;
typedef __attribute__((ext_vector_type(4))) float f32x4;
typedef __attribute__((ext_vector_type(16))) float f32x16;
typedef __attribute__((ext_vector_type(4))) unsigned int uint4v;

__device__ __forceinline__ short f2bf(float f) {
    unsigned u = __builtin_bit_cast(unsigned, f);
    return (short)((u + 0x8000u) >> 16);
}

// fp32 global (rows of 128) -> bf16 LDS tile, stride LDA (fallback path only).
template <int NT>
__device__ __forceinline__ void stage_tile(short* __restrict__ dst,
                                           const float* __restrict__ src,
                                           int nelts, int t) {
    for (int base = 0; base < nelts; base += NT * 8) {
        int flat = base + t * 8;
        const float4* p = (const float4*)(src + flat);
        float4 v0 = p[0];
        float4 v1 = p[1];
        bf16x8 s;
        s[0] = f2bf(v0.x); s[1] = f2bf(v0.y); s[2] = f2bf(v0.z); s[3] = f2bf(v0.w);
        s[4] = f2bf(v1.x); s[5] = f2bf(v1.y); s[6] = f2bf(v1.z); s[7] = f2bf(v1.w);
        int row = flat >> 7;
        int col = flat & 127;
        *(bf16x8*)&dst[row * LDA + col] = s;
    }
}

__global__ __launch_bounds__(256) void zero_kernel(float* __restrict__ p, int n) {
    int i = blockIdx.x * 256 + threadIdx.x;
    if (i < n) p[i] = 0.0f;
}

// ---------------------------------------------------------------------------
// Fast path
// ---------------------------------------------------------------------------

// grid = 2 tensors x 8 b x 64 rowgroups = 1024 blocks, 256 thr.
// Stages a 32-row fp32 tile -> bf16 LDS, then emits fragment records.
__global__ __launch_bounds__(256) void convert_kernel(const float* __restrict__ ctx,
                                                      const float* __restrict__ mn,
                                                      short* __restrict__ Cf,
                                                      short* __restrict__ Mf,
                                                      short* __restrict__ Ctf) {
    __shared__ short Ts[32 * TLD];

    int bid = blockIdx.x;
    int tsel = bid & 1;
    int b = (bid >> 1) & 7;
    int rg = bid >> 4;          // 0..63 : 32-row group
    int t = threadIdx.x;

    const float* src = (tsel ? mn : ctx) + ((size_t)(b * L_SEQ + rg * 32)) * DD;

    #pragma unroll
    for (int i = 0; i < 2; ++i) {
        int flat = i * 2048 + t * 8;
        int r = flat >> 7;
        int d = flat & 127;
        const float4* p = (const float4*)(src + flat);
        float4 v0 = p[0];
        float4 v1 = p[1];
        bf16x8 s;
        s[0] = f2bf(v0.x); s[1] = f2bf(v0.y); s[2] = f2bf(v0.z); s[3] = f2bf(v0.w);
        s[4] = f2bf(v1.x); s[5] = f2bf(v1.y); s[6] = f2bf(v1.z); s[7] = f2bf(v1.w);
        *(bf16x8*)&Ts[r * TLD + d] = s;
    }
    __syncthreads();

    if (tsel == 0) {
        int cs = rg >> 2;
        int ch = rg & 3;
        // Cf: 8 records (ks), 64 lane-slots each; 2 slots/thread.
        size_t cfb = (size_t)(((b * 16 + cs) * 4 + ch) * 8) * 512;
        #pragma unroll
        for (int i = 0; i < 2; ++i) {
            int slot = i * 256 + t;
            int ks = slot >> 6;
            int l2 = slot & 63;
            int la = l2 & 31;
            int hi = l2 >> 5;
            bf16x8 v = *(const bf16x8*)&Ts[la * TLD + (ks * 2 + hi) * 8];
            *(bf16x8*)&Cf[cfb + (size_t)ks * 512 + l2 * 8] = v;
        }
        // Ctf: 8 records (dg,ks2); transpose gather from LDS.
        size_t ctb = (size_t)((((b * 16 + cs) * 4 + ch) * 4) * 2) * 512;
        #pragma unroll
        for (int i = 0; i < 2; ++i) {
            int slot = i * 256 + t;
            int recl = slot >> 6;       // dg*2 + ks2
            int l2 = slot & 63;
            int dg = recl >> 1;
            int ks2 = recl & 1;
            int la = l2 & 31;
            int hi = l2 >> 5;
            int d = dg * 32 + la;
            int c0 = (ks2 * 2 + hi) * 8;     // local c row base
            bf16x8 v;
            #pragma unroll
            for (int j = 0; j < 8; ++j) v[j] = Ts[(c0 + j) * TLD + d];
            *(bf16x8*)&Ctf[ctb + (size_t)recl * 512 + l2 * 8] = v;
        }
    } else {
        // Mf: 8 records (ks); rowgroup rg = mw.
        size_t mfb = (size_t)((b * 64 + rg) * 8) * 512;
        #pragma unroll
        for (int i = 0; i < 2; ++i) {
            int slot = i * 256 + t;
            int ks = slot >> 6;
            int l2 = slot & 63;
            int la = l2 & 31;
            int hi = l2 >> 5;
            bf16x8 v = *(const bf16x8*)&Ts[la * TLD + (ks * 2 + hi) * 8];
            *(bf16x8*)&Mf[mfb + (size_t)ks * 512 + l2 * 8] = v;
        }
    }
}

// grid = 8 b x 32 ct2(64 c) = 256 blocks (b = bid&7), 512 thr (8 waves,
// 1 block/CU = 2 waves/SIMD). Swapped S: D[i=m][j=c=la] = mfma(Mf, Cf).
// c-tile 64: cf[2][8] hoisted, TWO independent accumulator chains per Mf
// load -> Mf traffic halves vs R16 (256->128 MB) and MFMA ILP doubles.
// No staging, no atomics; one 2 KB LDS reduce; writes invL directly.
__global__ __launch_bounds__(512) void stats_kernel(const short* __restrict__ Cf,
                                                    const short* __restrict__ Mf,
                                                    float* __restrict__ invLg) {
    __shared__ float red[8][2][32];

    int bid = blockIdx.x;
    int b = bid & 7;
    int ct2 = bid >> 3;         // 0..31 : 64-c tile
    int t = threadIdx.x;
    int w = t >> 6;             // 0..7
    int l = t & 63;
    int la = l & 31;

    // Hoist C B-frags for the two 32-c subtiles (ct = ct2*2 + j).
    bf16x8 cf[2][8];
    #pragma unroll
    for (int j = 0; j < 2; ++j) {
        int ct = ct2 * 2 + j;
        const short* cfp = Cf + (size_t)(((b * 16 + (ct >> 2)) * 4 + (ct & 3)) * 8) * 512 + l * 8;
        #pragma unroll
        for (int ks = 0; ks < 8; ++ks)
            cf[j][ks] = *(const bf16x8*)&cfp[(size_t)ks * 512];
    }

    float lacc0 = 0.0f, lacc1 = 0.0f;
    for (int i = 0; i < 8; ++i) {
        int mw = w * 8 + i;
        const short* mfp = Mf + (size_t)((b * 64 + mw) * 8) * 512 + l * 8;
        f32x16 s0, s1;
        #pragma unroll
        for (int r = 0; r < 16; ++r) { s0[r] = 0.0f; s1[r] = 0.0f; }
        #pragma unroll
        for (int ks = 0; ks < 8; ++ks) {
            bf16x8 av = *(const bf16x8*)&mfp[(size_t)ks * 512];
            s0 = __builtin_amdgcn_mfma_f32_32x32x16_bf16(av, cf[0][ks], s0, 0, 0, 0);
            s1 = __builtin_amdgcn_mfma_f32_32x32x16_bf16(av, cf[1][ks], s1, 0, 0, 0);
        }
        #pragma unroll
        for (int r = 0; r < 16; ++r) {
            lacc0 += __expf(s0[r] - SHIFT);
            lacc1 += __expf(s1[r] - SHIFT);
        }
    }

    // lanes l and l+32 hold the same c (col=la), disjoint m rows: combine,
    // then reduce the 8 waves through 2 KB LDS.
    lacc0 += __shfl_xor(lacc0, 32);
    lacc1 += __shfl_xor(lacc1, 32);
    if (l < 32) { red[w][0][la] = lacc0; red[w][1][la] = lacc1; }
    __syncthreads();
    if (t < 64) {
        int j = t >> 5;
        int c = t & 31;
        float L = 0.0f;
        #pragma unroll
        for (int ww = 0; ww < 8; ++ww) L += red[ww][j][c];
        invLg[(size_t)b * L_SEQ + ct2 * 64 + j * 32 + c] = 1.0f / L;
    }
}

// grid = 8 b x 64 mtiles(32 m) = 512 blocks (b = bid&7), 256 thr = 4 waves
// (4 c-slices). ALL operands are coalesced records; NO barriers in the main
// loop. LDS 64 KB only for the epilogue cross-slice reduction (2 blocks/CU).
__global__ __launch_bounds__(256, 2) void attend_fused(const short* __restrict__ Cf,
                                                       const short* __restrict__ Mf,
                                                       const short* __restrict__ Ctf,
                                                       const float* __restrict__ invLg,
                                                       const float* __restrict__ mn,
                                                       float* __restrict__ out) {
    __shared__ float red[4][4096];

    int bid = blockIdx.x;
    int b = bid & 7;
    int mtile = bid >> 3;       // 0..63
    int t = threadIdx.x;
    int w = t >> 6;             // ch
    int l = t & 63;
    int la = l & 31;
    int hi = l >> 5;
    int ch = w;

    // Hoist M B-frags from Mf record (mw = mtile) — same records stats read.
    bf16x8 mf[8];
    {
        const short* mfp = Mf + (size_t)((b * 64 + mtile) * 8) * 512 + l * 8;
        #pragma unroll
        for (int ks = 0; ks < 8; ++ks)
            mf[ks] = *(const bf16x8*)&mfp[(size_t)ks * 512];
    }

    f32x16 o[4];
    #pragma unroll
    for (int dg = 0; dg < 4; ++dg)
        #pragma unroll
        for (int r = 0; r < 16; ++r) o[dg][r] = 0.0f;

    const float* ilbase = invLg + (size_t)b * L_SEQ + ch * 32 + hi * 4;

    for (int cs = 0; cs < 16; ++cs) {
        const short* cfp = Cf + (size_t)(((b * 16 + cs) * 4 + ch) * 8) * 512 + l * 8;
        const short* tfp = Ctf + (size_t)((((b * 16 + cs) * 4 + ch) * 4) * 2) * 512 + l * 8;

        // PV A-frags: 8 coalesced record loads (independent of S, fly early).
        bf16x8 tv[4][2];
        #pragma unroll
        for (int dg = 0; dg < 4; ++dg)
            #pragma unroll
            for (int ks2 = 0; ks2 < 2; ++ks2)
                tv[dg][ks2] = *(const bf16x8*)&tfp[(size_t)(dg * 2 + ks2) * 512];

        // invL for this window's 16 c's per lane (broadcast float4 loads).
        f32x4 ilv[4];
        #pragma unroll
        for (int q = 0; q < 4; ++q)
            ilv[q] = *(const f32x4*)&ilbase[cs * 128 + q * 8];

        // S-GEMM (swapped): D[i=c][j=m=la], A = Cf records.
        f32x16 s;
        #pragma unroll
        for (int r = 0; r < 16; ++r) s[r] = 0.0f;
        #pragma unroll
        for (int ks = 0; ks < 8; ++ks) {
            bf16x8 av = *(const bf16x8*)&cfp[(size_t)ks * 512];
            s = __builtin_amdgcn_mfma_f32_32x32x16_bf16(av, mf[ks], s, 0, 0, 0);
        }

        // P = exp(S-40) * invL[c] -> bf16 pairs. reg r=q*4+sub: c_local = sub+8q+4hi.
        unsigned u[4][2];
        #pragma unroll
        for (int q = 0; q < 4; ++q)
            #pragma unroll
            for (int jj = 0; jj < 2; ++jj) {
                float e0 = __expf(s[q * 4 + jj * 2]     - SHIFT) * ilv[q][jj * 2];
                float e1 = __expf(s[q * 4 + jj * 2 + 1] - SHIFT) * ilv[q][jj * 2 + 1];
                u[q][jj] = ((unsigned)(unsigned short)f2bf(e1) << 16)
                         |  (unsigned)(unsigned short)f2bf(e0);
            }

        // Half-wave exchange -> PV B-frags (c_local = ks2*16 + hi*8 + 0..7).
        bf16x8 pa[2];
        #pragma unroll
        for (int ks2 = 0; ks2 < 2; ++ks2) {
            unsigned a0 = u[2 * ks2][0],     a1 = u[2 * ks2][1];
            unsigned b0 = u[2 * ks2 + 1][0], b1 = u[2 * ks2 + 1][1];
            unsigned a0p = (unsigned)__shfl_xor((int)a0, 32);
            unsigned a1p = (unsigned)__shfl_xor((int)a1, 32);
            unsigned b0p = (unsigned)__shfl_xor((int)b0, 32);
            unsigned b1p = (unsigned)__shfl_xor((int)b1, 32);
            uint4v pw;
            pw.x = hi ? b0p : a0;
            pw.y = hi ? b1p : a1;
            pw.z = hi ? b0  : a0p;
            pw.w = hi ? b1  : a1p;
            pa[ks2] = __builtin_bit_cast(bf16x8, pw);
        }

        // PV: D2[i=d][j=m], A = tv (Ctf records), B = pa.
        #pragma unroll
        for (int dg = 0; dg < 4; ++dg)
            #pragma unroll
            for (int ks2 = 0; ks2 < 2; ++ks2)
                o[dg] = __builtin_amdgcn_mfma_f32_32x32x16_bf16(tv[dg][ks2], pa[ks2], o[dg], 0, 0, 0);
    }

    // Epilogue: per-wave partials -> LDS, sum 4 c-slices, out = main - sum.
    {
        float* base = red[w];
        #pragma unroll
        for (int dg = 0; dg < 4; ++dg)
            #pragma unroll
            for (int r = 0; r < 16; ++r) {
                int d = dg * 32 + (r & 3) + 8 * (r >> 2) + 4 * hi;
                base[d * 32 + la] = o[dg][r];
            }
    }
    __syncthreads();

    {
        int m  = t & 31;
        int dq = t >> 5;
        size_t gbase = ((size_t)(b * L_SEQ + mtile * 32 + m)) * DD + dq * 16;
        #pragma unroll
        for (int jq = 0; jq < 4; ++jq) {
            f32x4 v;
            #pragma unroll
            for (int e = 0; e < 4; ++e) {
                int idx = (dq * 16 + jq * 4 + e) * 32 + m;
                v[e] = red[0][idx] + red[1][idx] + red[2][idx] + red[3][idx];
            }
            f32x4 mv = *(const f32x4*)&mn[gbase + jq * 4];
            f32x4 ov;
            ov[0] = mv[0] - v[0]; ov[1] = mv[1] - v[1];
            ov[2] = mv[2] - v[2]; ov[3] = mv[3] - v[3];
            *(f32x4*)&out[gbase + jq * 4] = ov;
        }
    }
}

// ---------------------------------------------------------------------------
// Fallback path (round-2 kernels, tiny workspace)
// ---------------------------------------------------------------------------

__global__ __launch_bounds__(256, 4) void stats_fb(const float* __restrict__ ctx,
                                                   const float* __restrict__ mn,
                                                   float* __restrict__ Lg) {
    __shared__ short Cs[64 * LDA];
    __shared__ short Ms[64 * LDA];

    int bid = blockIdx.x;
    int mc = bid & 3;
    int ct = (bid >> 2) & 31;
    int b  = bid >> 7;
    int t = threadIdx.x;
    int w = t >> 6;
    int l = t & 63;
    int a15 = l & 15;
    int q = l >> 4;

    stage_tile<256>(Cs, ctx + ((size_t)b * L_SEQ + ct * 64) * DD, 64 * DD, t);

    float ls[4] = {0.f, 0.f, 0.f, 0.f};
    for (int mt = 0; mt < 8; ++mt) {
        __syncthreads();
        int m0 = (mc * 8 + mt) * 64;
        stage_tile<256>(Ms, mn + ((size_t)b * L_SEQ + m0) * DD, 64 * DD, t);
        __syncthreads();

        f32x4 acc[4] = {{0.f,0.f,0.f,0.f},{0.f,0.f,0.f,0.f},{0.f,0.f,0.f,0.f},{0.f,0.f,0.f,0.f}};
        #pragma unroll
        for (int ks = 0; ks < 4; ++ks) {
            int k0 = ks * 32 + q * 8;
            bf16x8 a = *(const bf16x8*)&Cs[(w * 16 + a15) * LDA + k0];
            #pragma unroll
            for (int g = 0; g < 4; ++g) {
                bf16x8 bb = *(const bf16x8*)&Ms[(g * 16 + a15) * LDA + k0];
                acc[g] = __builtin_amdgcn_mfma_f32_16x16x32_bf16(a, bb, acc[g], 0, 0, 0);
            }
        }
        #pragma unroll
        for (int g = 0; g < 4; ++g)
            #pragma unroll
            for (int r = 0; r < 4; ++r)
                ls[r] += __expf(acc[g][r] - SHIFT);
    }

    #pragma unroll
    for (int r = 0; r < 4; ++r) {
        float v = ls[r];
        v += __shfl_xor(v, 1);
        v += __shfl_xor(v, 2);
        v += __shfl_xor(v, 4);
        v += __shfl_xor(v, 8);
        ls[r] = v;
    }
    if (a15 == 0) {
        int c = ct * 64 + w * 16 + q * 4;
        #pragma unroll
        for (int r = 0; r < 4; ++r)
            atomicAdd(&Lg[(size_t)b * L_SEQ + c + r], ls[r]);
    }
}

__global__ __launch_bounds__(1024, 4) void attend_fb(const float* __restrict__ ctx,
                                                     const float* __restrict__ mn,
                                                     const float* __restrict__ Lg,
                                                     float* __restrict__ out) {
    __shared__ short Mt[64 * LDA];
    __shared__ short Cs[128 * LDA];
    __shared__ short Ct[128 * LDA];
    __shared__ short Ps[64 * LDA];
    __shared__ float invLs[128];

    int bid = blockIdx.x;
    int mtile = bid & 31;
    int b = bid >> 5;
    int m0 = mtile * 64;
    int t = threadIdx.x;
    int w = t >> 6;
    int l = t & 63;
    int a15 = l & 15;
    int q = l >> 4;
    int mg = w & 3;
    int pg = w >> 2;

    stage_tile<1024>(Mt, mn + ((size_t)b * L_SEQ + m0) * DD, 64 * DD, t);

    f32x4 oacc[2] = {{0.f,0.f,0.f,0.f},{0.f,0.f,0.f,0.f}};

    for (int cs = 0; cs < 16; ++cs) {
        int c0 = cs * 128;
        __syncthreads();
        stage_tile<1024>(Cs, ctx + ((size_t)b * L_SEQ + c0) * DD, 128 * DD, t);
        if (t < 128) invLs[t] = 1.0f / Lg[(size_t)b * L_SEQ + c0 + t];
        __syncthreads();

        {
            int cc = t & 127;
            int d0 = (t >> 7) * 16;
            #pragma unroll
            for (int hh = 0; hh < 2; ++hh) {
                bf16x8 v = *(const bf16x8*)&Cs[cc * LDA + d0 + hh * 8];
                #pragma unroll
                for (int j = 0; j < 8; ++j)
                    Ct[(d0 + hh * 8 + j) * LDA + cc] = v[j];
            }
        }

        f32x4 sacc[2] = {{0.f,0.f,0.f,0.f},{0.f,0.f,0.f,0.f}};
        #pragma unroll
        for (int ks = 0; ks < 4; ++ks) {
            int k0 = ks * 32 + q * 8;
            bf16x8 a = *(const bf16x8*)&Mt[(mg * 16 + a15) * LDA + k0];
            #pragma unroll
            for (int g = 0; g < 2; ++g) {
                bf16x8 bb = *(const bf16x8*)&Cs[((pg * 2 + g) * 16 + a15) * LDA + k0];
                sacc[g] = __builtin_amdgcn_mfma_f32_16x16x32_bf16(a, bb, sacc[g], 0, 0, 0);
            }
        }
        #pragma unroll
        for (int g = 0; g < 2; ++g) {
            int cl = (pg * 2 + g) * 16 + a15;
            float il = invLs[cl];
            #pragma unroll
            for (int r = 0; r < 4; ++r) {
                float p = __expf(sacc[g][r] - SHIFT) * il;
                Ps[(mg * 16 + q * 4 + r) * LDA + cl] = f2bf(p);
            }
        }
        __syncthreads();

        #pragma unroll
        for (int ks = 0; ks < 4; ++ks) {
            int k0 = ks * 32 + q * 8;
            bf16x8 a = *(const bf16x8*)&Ps[(mg * 16 + a15) * LDA + k0];
            #pragma unroll
            for (int g = 0; g < 2; ++g) {
                bf16x8 bb = *(const bf16x8*)&Ct[((pg * 2 + g) * 16 + a15) * LDA + k0];
                oacc[g] = __builtin_amdgcn_mfma_f32_16x16x32_bf16(a, bb, oacc[g], 0, 0, 0);
            }
        }
    }

    #pragma unroll
    for (int g = 0; g < 2; ++g) {
        int dl = (pg * 2 + g) * 16 + a15;
        #pragma unroll
        for (int r = 0; r < 4; ++r) {
            int ml = mg * 16 + q * 4 + r;
            size_t idx = ((size_t)b * L_SEQ + m0 + ml) * DD + dl;
            out[idx] = mn[idx] - oacc[g][r];
        }
    }
}

// ---------------------------------------------------------------------------

extern "C" void kernel_launch(void* const* d_in, const int* in_sizes, int n_in,
                              void* d_out, int out_size, void* d_ws, size_t ws_size,
                              hipStream_t stream) {
    const float* ctx = (const float*)d_in[0];  // (B, Lc, D)
    const float* mn  = (const float*)d_in[1];  // (B, Lm, D)
    float* out = (float*)d_out;                // (B, Lm, D)

    // Workspace: invLg 64 KB | Cf 4 MB | Mf 4 MB | Ctf 4 MB
    const size_t LG_BYTES = (size_t)BATCH * L_SEQ * sizeof(float);
    const size_t BF_BYTES = (size_t)BATCH * L_SEQ * DD * sizeof(short);
    const size_t NEED = LG_BYTES + 3 * BF_BYTES;

    float* Lg = (float*)d_ws;

    if (ws_size >= NEED) {
        short* Cf  = (short*)((char*)d_ws + LG_BYTES);
        short* Mf  = (short*)((char*)d_ws + LG_BYTES + BF_BYTES);
        short* Ctf = (short*)((char*)d_ws + LG_BYTES + 2 * BF_BYTES);
        convert_kernel<<<1024, 256, 0, stream>>>(ctx, mn, Cf, Mf, Ctf);
        stats_kernel<<<256, 512, 0, stream>>>(Cf, Mf, Lg);
        attend_fused<<<512, 256, 0, stream>>>(Cf, Mf, Ctf, Lg, mn, out);
    } else {
        int nL = BATCH * L_SEQ;
        zero_kernel<<<(nL + 255) / 256, 256, 0, stream>>>(Lg, nL);
        stats_fb<<<BATCH * 32 * 4, 256, 0, stream>>>(ctx, mn, Lg);
        attend_fb<<<BATCH * 32, 1024, 0, stream>>>(ctx, mn, Lg, out);
    }
}